// Round 1
// baseline (663.119 us; speedup 1.0000x reference)
//
#include <hip/hip_runtime.h>
#include <math.h>

#define F 256
#define Hh 128
#define MAXL 3072

// ---------------------------------------------------------------------------
// K0: zero the 'out' region of d_out, compute exclusive prefix offsets of
// lengths (block 0 only; Hillis-Steele scan in LDS).
// ---------------------------------------------------------------------------
__global__ void init_kernel(const int* __restrict__ lengths, int* __restrict__ offsets,
                            float* __restrict__ out, int S, int outN) {
  int t = blockIdx.x * blockDim.x + threadIdx.x;
  for (int i = t; i < outN; i += gridDim.x * blockDim.x) out[i] = 0.f;
  if (blockIdx.x == 0) {
    __shared__ int buf[256];
    int tid = threadIdx.x;
    int v = (tid < S) ? lengths[tid] : 0;
    buf[tid] = v;
    __syncthreads();
    for (int o = 1; o < 256; o <<= 1) {
      int add = (tid >= o) ? buf[tid - o] : 0;
      __syncthreads();
      buf[tid] += add;
      __syncthreads();
    }
    if (tid < S) offsets[tid] = buf[tid] - v;   // exclusive
    if (tid == S - 1) offsets[S] = buf[tid];    // total N
  }
}

// ---------------------------------------------------------------------------
// K1: fused MLP.  y[i], z[i] = tanh(x[i]@W1 + b1) @ W2 + b2
// 128x128 block tile (rows x hidden), 256 threads, 8x8 micro-tile, K-chunk 32.
// h is never materialized to global: epilogue contracts with W2 in-register,
// then reduces across the 16 col-group threads via LDS.
// ---------------------------------------------------------------------------
__global__ __launch_bounds__(256) void mlp_kernel(
    const float* __restrict__ x, const float* __restrict__ W1,
    const float* __restrict__ b1, const float* __restrict__ W2,
    const float* __restrict__ b2, float* __restrict__ yv,
    float* __restrict__ zv, int N) {
  __shared__ float xs[32][132];   // x tile, transposed [k][row], padded (16B-aligned rows)
  __shared__ float ws[32][128];   // W1 tile [k][j]
  __shared__ float red[128][17];  // epilogue reduction

  const int t  = threadIdx.x;
  const int tx = t & 15;          // col group: cols tx*8 .. tx*8+7
  const int ty = t >> 4;          // row group: rows ty*8 .. ty*8+7
  const int row0 = blockIdx.x * 128;

  float acc[8][8];
#pragma unroll
  for (int i = 0; i < 8; ++i)
#pragma unroll
    for (int j = 0; j < 8; ++j) acc[i][j] = 0.f;

  const int k4 = (t & 7) * 4;     // k offset for x-tile load
  const int rb = t >> 3;          // row 0..31 for x-tile load
  const int j4 = (t & 31) * 4;    // j offset for W1-tile load
  const int kb = t >> 5;          // k 0..7 for W1-tile load

  for (int kc = 0; kc < F; kc += 32) {
    // stage x tile (coalesced float4 along k), store transposed
#pragma unroll
    for (int i = 0; i < 4; ++i) {
      int r = rb + 32 * i;
      int g = row0 + r;
      float4 v = make_float4(0.f, 0.f, 0.f, 0.f);
      if (g < N) v = *(const float4*)&x[(size_t)g * F + kc + k4];
      xs[k4 + 0][r] = v.x; xs[k4 + 1][r] = v.y;
      xs[k4 + 2][r] = v.z; xs[k4 + 3][r] = v.w;
    }
    // stage W1 tile (already k-major, coalesced float4)
#pragma unroll
    for (int i = 0; i < 4; ++i) {
      int k = kb + 8 * i;
      *(float4*)&ws[k][j4] = *(const float4*)&W1[(size_t)(kc + k) * Hh + j4];
    }
    __syncthreads();
#pragma unroll
    for (int kk = 0; kk < 32; ++kk) {
      float a[8], b[8];
      *(float4*)&a[0] = *(const float4*)&xs[kk][ty * 8];
      *(float4*)&a[4] = *(const float4*)&xs[kk][ty * 8 + 4];
      *(float4*)&b[0] = *(const float4*)&ws[kk][tx * 8];
      *(float4*)&b[4] = *(const float4*)&ws[kk][tx * 8 + 4];
#pragma unroll
      for (int i = 0; i < 8; ++i)
#pragma unroll
        for (int j = 0; j < 8; ++j) acc[i][j] = fmaf(a[i], b[j], acc[i][j]);
    }
    __syncthreads();
  }

  // epilogue: h = tanh(acc + b1); y/z partials over this thread's 8 cols
  float bb[8], wy[8], wz[8];
#pragma unroll
  for (int j = 0; j < 8; ++j) {
    int c = tx * 8 + j;
    bb[j] = b1[c];
    wy[j] = W2[c * 2 + 0];
    wz[j] = W2[c * 2 + 1];
  }
  float yp[8], zp[8];
#pragma unroll
  for (int i = 0; i < 8; ++i) {
    float sy = 0.f, sz = 0.f;
#pragma unroll
    for (int j = 0; j < 8; ++j) {
      float h = tanhf(acc[i][j] + bb[j]);
      sy = fmaf(h, wy[j], sy);
      sz = fmaf(h, wz[j], sz);
    }
    yp[i] = sy; zp[i] = sz;
  }
  // reduce across the 16 col-group threads per row: y
#pragma unroll
  for (int i = 0; i < 8; ++i) red[ty * 8 + i][tx] = yp[i];
  __syncthreads();
  if (t < 128) {
    float s = 0.f;
#pragma unroll
    for (int q = 0; q < 16; ++q) s += red[t][q];
    int g = row0 + t;
    if (g < N) yv[g] = s + b2[0];
  }
  __syncthreads();
#pragma unroll
  for (int i = 0; i < 8; ++i) red[ty * 8 + i][tx] = zp[i];
  __syncthreads();
  if (t < 128) {
    float s = 0.f;
#pragma unroll
    for (int q = 0; q < 16; ++q) s += red[t][q];
    int g = row0 + t;
    if (g < N) zv[g] = s + b2[1];
  }
}

// ---------------------------------------------------------------------------
// K2: per-segment stats + attention weights.  One block per segment.
// y,z cached in LDS (L <= 3072).  Computes ymax, softmax-weighted position
// mean, softplus std, Gaussian pdf, psum, writes attn = pdf/(psum+1e-3).
// ---------------------------------------------------------------------------
__device__ inline float wave_reduce_sum(float v) {
#pragma unroll
  for (int o = 32; o; o >>= 1) v += __shfl_down(v, o);
  return v;
}
__device__ inline float wave_reduce_max(float v) {
#pragma unroll
  for (int o = 32; o; o >>= 1) v = fmaxf(v, __shfl_down(v, o));
  return v;
}

__global__ __launch_bounds__(256) void stats_kernel(
    const float* __restrict__ yv, const float* __restrict__ zv,
    const int* __restrict__ offsets, const int* __restrict__ lengths,
    float* __restrict__ attn) {
  __shared__ float ybuf[MAXL];
  __shared__ float zbuf[MAXL];
  __shared__ float redA[4], redB[4], redC[4];
  const int s = blockIdx.x;
  const int off = offsets[s];
  const int L = lengths[s];
  const int t = threadIdx.x;
  const int lane = t & 63, wid = t >> 6;

  float lmax = -1e30f;
  for (int i = t; i < L; i += 256) {
    float yy = yv[off + i];
    ybuf[i] = yy;
    zbuf[i] = zv[off + i];
    lmax = fmaxf(lmax, yy);
  }
  lmax = wave_reduce_max(lmax);
  if (lane == 0) redA[wid] = lmax;
  __syncthreads();
  const float ymax = fmaxf(fmaxf(redA[0], redA[1]), fmaxf(redA[2], redA[3]));
  const float invL = 1.f / (float)L;
  __syncthreads();  // all reads of redA done before reuse

  float sw = 0.f, smx = 0.f, sz = 0.f;
  for (int i = t; i < L; i += 256) {
    float w = expf(ybuf[i] - ymax);
    float xp = (float)(i + 1) * invL;
    sw += w;
    smx = fmaf(xp, w, smx);
    sz += zbuf[i];
  }
  sw = wave_reduce_sum(sw);
  smx = wave_reduce_sum(smx);
  sz = wave_reduce_sum(sz);
  if (lane == 0) { redA[wid] = sw; redB[wid] = smx; redC[wid] = sz; }
  __syncthreads();
  const float wsum = redA[0] + redA[1] + redA[2] + redA[3];
  const float mxs  = redB[0] + redB[1] + redB[2] + redB[3];
  const float zsum = redC[0] + redC[1] + redC[2] + redC[3];
  const float mu = mxs / wsum;
  const float tz = zsum * invL;
  const float sd = fmaxf(tz, 0.f) + log1pf(expf(-fabsf(tz)));  // softplus
  const float invsd = 1.f / sd;
  const float C = 0.3989422804014327f;  // 1/sqrt(2*pi)
  __syncthreads();  // all reads of redA done before reuse

  float ps = 0.f;
  for (int i = t; i < L; i += 256) {
    float xp = (float)(i + 1) * invL;
    float u = (xp - mu) * invsd;
    float p = expf(-0.5f * u * u) * (C * invsd);
    ybuf[i] = p;   // same-thread indices only, no cross-thread hazard
    ps += p;
  }
  ps = wave_reduce_sum(ps);
  if (lane == 0) redA[wid] = ps;
  __syncthreads();
  const float psum = redA[0] + redA[1] + redA[2] + redA[3];
  const float sc = 1.f / (psum + 0.001f);
  for (int i = t; i < L; i += 256) attn[off + i] = ybuf[i] * sc;
}

// ---------------------------------------------------------------------------
// K3: pooled output.  out[s,f] = sum_i attn_i * x[i,f].
// Grid (S, 16 chunks); thread = one feature; atomicAdd partials.
// HBM-bound: streams x once, coalesced 256-thread rows.
// ---------------------------------------------------------------------------
__global__ __launch_bounds__(256) void pool_kernel(
    const float* __restrict__ x, const float* __restrict__ attn,
    const int* __restrict__ offsets, const int* __restrict__ lengths,
    float* __restrict__ out, int nchunks) {
  const int s = blockIdx.x, c = blockIdx.y;
  const int off = offsets[s], L = lengths[s];
  const int i0 = (int)((long long)L * c / nchunks);
  const int i1 = (int)((long long)L * (c + 1) / nchunks);
  const int f = threadIdx.x;
  float acc[4] = {0.f, 0.f, 0.f, 0.f};
  int i = i0;
  for (; i + 3 < i1; i += 4) {
#pragma unroll
    for (int q = 0; q < 4; ++q)
      acc[q] = fmaf(attn[off + i + q], x[(size_t)(off + i + q) * F + f], acc[q]);
  }
  for (; i < i1; ++i)
    acc[0] = fmaf(attn[off + i], x[(size_t)(off + i) * F + f], acc[0]);
  float a = (acc[0] + acc[1]) + (acc[2] + acc[3]);
  atomicAdd(&out[s * F + f], a);
}

// ---------------------------------------------------------------------------
extern "C" void kernel_launch(void* const* d_in, const int* in_sizes, int n_in,
                              void* d_out, int out_size, void* d_ws, size_t ws_size,
                              hipStream_t stream) {
  const float* x      = (const float*)d_in[0];
  const int* lengths  = (const int*)d_in[1];
  const float* W1     = (const float*)d_in[2];
  const float* b1     = (const float*)d_in[3];
  const float* W2     = (const float*)d_in[4];
  const float* b2     = (const float*)d_in[5];
  const int S = in_sizes[1];
  const int N = in_sizes[0] / F;

  float* out  = (float*)d_out;             // S*F
  float* attn = out + (size_t)S * F;       // N

  int*   offsets = (int*)d_ws;             // S+1 ints
  float* yv = (float*)d_ws + 512;          // N floats
  float* zv = yv + N;                      // N floats

  init_kernel<<<64, 256, 0, stream>>>(lengths, offsets, out, S, S * F);
  mlp_kernel<<<(N + 127) / 128, 256, 0, stream>>>(x, W1, b1, W2, b2, yv, zv, N);
  stats_kernel<<<S, 256, 0, stream>>>(yv, zv, offsets, lengths, attn);
  pool_kernel<<<dim3(S, 16), 256, 0, stream>>>(x, attn, offsets, lengths, out, 16);
}

// Round 2
// 512.697 us; speedup vs baseline: 1.2934x; 1.2934x over previous
//
#include <hip/hip_runtime.h>
#include <math.h>

#define F 256
#define Hh 128
#define MAXL 3072

typedef short bf16x8 __attribute__((ext_vector_type(8)));
typedef float f32x4 __attribute__((ext_vector_type(4)));
typedef unsigned short ushort4v __attribute__((ext_vector_type(4)));
typedef unsigned short ushort8v __attribute__((ext_vector_type(8)));

__device__ inline unsigned short f2bf_rne(float f) {
  unsigned u = __float_as_uint(f);
  unsigned r = u + 0x7fff + ((u >> 16) & 1);
  return (unsigned short)(r >> 16);
}
__device__ inline float bf2f(unsigned short h) {
  return __uint_as_float((unsigned)h << 16);
}

// ---------------------------------------------------------------------------
// K0: zero out, prefix-scan lengths, and split W1 into bf16 hi/lo transposed
// chunk-major:  whT[chunk][col][k]  (chunk = k/32, k local 0..31), 8 chunks.
// ---------------------------------------------------------------------------
__global__ void init_kernel(const int* __restrict__ lengths, int* __restrict__ offsets,
                            float* __restrict__ out, const float* __restrict__ W1,
                            unsigned short* __restrict__ whT, unsigned short* __restrict__ wlT,
                            int S, int outN) {
  int t = blockIdx.x * blockDim.x + threadIdx.x;
  int stride = gridDim.x * blockDim.x;
  for (int i = t; i < outN; i += stride) out[i] = 0.f;
  // W1 split-transpose: W1 is [k=256][col=128]
  for (int i = t; i < F * Hh; i += stride) {
    int k = i >> 7, col = i & 127;
    float v = W1[i];
    unsigned short h = f2bf_rne(v);
    unsigned short l = f2bf_rne(v - bf2f(h));
    int dst = (k >> 5) * (128 * 32) + col * 32 + (k & 31);
    whT[dst] = h;
    wlT[dst] = l;
  }
  if (blockIdx.x == 0) {
    __shared__ int buf[256];
    int tid = threadIdx.x;
    int v = (tid < S) ? lengths[tid] : 0;
    buf[tid] = v;
    __syncthreads();
    for (int o = 1; o < 256; o <<= 1) {
      int add = (tid >= o) ? buf[tid - o] : 0;
      __syncthreads();
      buf[tid] += add;
      __syncthreads();
    }
    if (tid < S) offsets[tid] = buf[tid] - v;   // exclusive
    if (tid == S - 1) offsets[S] = buf[tid];    // total N
  }
}

// ---------------------------------------------------------------------------
// K1: fused MLP via MFMA (bf16 split precision, 3 passes: hh + hl + lh).
// Block tile 128 rows x 128 cols, 4 waves (2x2), each wave 64x64 = 4x4
// 16x16x32 mfma tiles.  K = 256 in 8 chunks of 32.
// Epilogue: tanh + W2 contraction + LDS reduction -> y,z per row.
// ---------------------------------------------------------------------------
__global__ __launch_bounds__(256) void mlp_kernel(
    const float* __restrict__ x,
    const unsigned short* __restrict__ whT, const unsigned short* __restrict__ wlT,
    const float* __restrict__ b1, const float* __restrict__ W2,
    const float* __restrict__ b2, float* __restrict__ yv,
    float* __restrict__ zv, int N) {
  // LDS pool: 4 tiles of [128][40] shorts (stride 40 breaks pow-2 banks),
  // reused as float red[128][33] in the epilogue.
  __shared__ __align__(16) char SMEM[40960];
  unsigned short* xh = (unsigned short*)SMEM;   // [128][40]
  unsigned short* xl = xh + 5120;
  unsigned short* wh = xh + 10240;
  unsigned short* wl = xh + 15360;
  float* red = (float*)SMEM;                    // [128][33] (16896 B, reused)

  const int t = threadIdx.x;
  const int lane = t & 63;
  const int w = t >> 6;
  const int wr = w >> 1, wc = w & 1;           // wave grid 2x2
  const int ln15 = lane & 15, lq = lane >> 4;  // quad

  const int row0 = blockIdx.x * 128;

  f32x4 acc[4][4];  // [rt][ct]
#pragma unroll
  for (int i = 0; i < 4; ++i)
#pragma unroll
    for (int j = 0; j < 4; ++j) acc[i][j] = (f32x4){0.f, 0.f, 0.f, 0.f};

  const int xr = t >> 3;          // 0..31
  const int xk = (t & 7) * 4;     // 0,4,..,28

  for (int kc = 0; kc < 8; ++kc) {
    // ---- stage x tile: 128 rows x 32 k, fp32 -> bf16 hi/lo ----
#pragma unroll
    for (int i = 0; i < 4; ++i) {
      int r = xr + 32 * i;
      int g = row0 + r;
      float4 v = make_float4(0.f, 0.f, 0.f, 0.f);
      if (g < N) v = *(const float4*)&x[(size_t)g * F + kc * 32 + xk];
      ushort4v hv, lv;
      float f[4] = {v.x, v.y, v.z, v.w};
#pragma unroll
      for (int q = 0; q < 4; ++q) {
        unsigned short h = f2bf_rne(f[q]);
        hv[q] = h;
        lv[q] = f2bf_rne(f[q] - bf2f(h));
      }
      *(ushort4v*)&xh[r * 40 + xk] = hv;
      *(ushort4v*)&xl[r * 40 + xk] = lv;
    }
    // ---- stage W1 tile: pre-split chunk-major, 16B copies ----
#pragma unroll
    for (int i = 0; i < 2; ++i) {
      int idx = t + 256 * i;                 // 0..511
      int col = idx >> 2, k8 = (idx & 3) * 8;
      ushort8v vh = *(const ushort8v*)&whT[kc * 4096 + idx * 8];
      ushort8v vl = *(const ushort8v*)&wlT[kc * 4096 + idx * 8];
      *(ushort8v*)&wh[col * 40 + k8] = vh;
      *(ushort8v*)&wl[col * 40 + k8] = vl;
    }
    __syncthreads();
    // ---- MFMA: 4x4 tiles x 3 passes ----
    bf16x8 bh[4], bl[4];
#pragma unroll
    for (int ct = 0; ct < 4; ++ct) {
      int c = wc * 64 + ct * 16 + ln15;
      bh[ct] = *(const bf16x8*)&wh[c * 40 + lq * 8];
      bl[ct] = *(const bf16x8*)&wl[c * 40 + lq * 8];
    }
#pragma unroll
    for (int rt = 0; rt < 4; ++rt) {
      int r = wr * 64 + rt * 16 + ln15;
      bf16x8 ah = *(const bf16x8*)&xh[r * 40 + lq * 8];
      bf16x8 al = *(const bf16x8*)&xl[r * 40 + lq * 8];
#pragma unroll
      for (int ct = 0; ct < 4; ++ct) {
        acc[rt][ct] = __builtin_amdgcn_mfma_f32_16x16x32_bf16(ah, bh[ct], acc[rt][ct], 0, 0, 0);
        acc[rt][ct] = __builtin_amdgcn_mfma_f32_16x16x32_bf16(ah, bl[ct], acc[rt][ct], 0, 0, 0);
        acc[rt][ct] = __builtin_amdgcn_mfma_f32_16x16x32_bf16(al, bh[ct], acc[rt][ct], 0, 0, 0);
      }
    }
    __syncthreads();
  }

  // ---- epilogue: h = tanh(acc + b1), contract with W2 ----
  // acc[rt][ct][rg]: row = wr*64 + rt*16 + lq*4 + rg, col = wc*64 + ct*16 + ln15
  float yp[4][4], zp[4][4];
#pragma unroll
  for (int i = 0; i < 4; ++i)
#pragma unroll
    for (int j = 0; j < 4; ++j) { yp[i][j] = 0.f; zp[i][j] = 0.f; }
#pragma unroll
  for (int ct = 0; ct < 4; ++ct) {
    int c = wc * 64 + ct * 16 + ln15;
    float b1c = b1[c], wyc = W2[2 * c], wzc = W2[2 * c + 1];
#pragma unroll
    for (int rt = 0; rt < 4; ++rt)
#pragma unroll
      for (int rg = 0; rg < 4; ++rg) {
        float a = acc[rt][ct][rg] + b1c;
        float e = __expf(2.f * a);
        float h = 1.f - __fdividef(2.f, e + 1.f);   // tanh(a)
        yp[rt][rg] = fmaf(h, wyc, yp[rt][rg]);
        zp[rt][rg] = fmaf(h, wzc, zp[rt][rg]);
      }
  }
  // reduce y across 32 col-partials per row via LDS (reuses tile memory)
#pragma unroll
  for (int rt = 0; rt < 4; ++rt)
#pragma unroll
    for (int rg = 0; rg < 4; ++rg)
      red[(wr * 64 + rt * 16 + lq * 4 + rg) * 33 + wc * 16 + ln15] = yp[rt][rg];
  __syncthreads();
  if (t < 128) {
    float s = 0.f;
#pragma unroll
    for (int q = 0; q < 32; ++q) s += red[t * 33 + q];
    int g = row0 + t;
    if (g < N) yv[g] = s + b2[0];
  }
  __syncthreads();
#pragma unroll
  for (int rt = 0; rt < 4; ++rt)
#pragma unroll
    for (int rg = 0; rg < 4; ++rg)
      red[(wr * 64 + rt * 16 + lq * 4 + rg) * 33 + wc * 16 + ln15] = zp[rt][rg];
  __syncthreads();
  if (t < 128) {
    float s = 0.f;
#pragma unroll
    for (int q = 0; q < 32; ++q) s += red[t * 33 + q];
    int g = row0 + t;
    if (g < N) zv[g] = s + b2[1];
  }
}

// ---------------------------------------------------------------------------
// K2: per-segment stats + attention weights.  One block per segment.
// ---------------------------------------------------------------------------
__device__ inline float wave_reduce_sum(float v) {
#pragma unroll
  for (int o = 32; o; o >>= 1) v += __shfl_down(v, o);
  return v;
}
__device__ inline float wave_reduce_max(float v) {
#pragma unroll
  for (int o = 32; o; o >>= 1) v = fmaxf(v, __shfl_down(v, o));
  return v;
}

__global__ __launch_bounds__(256) void stats_kernel(
    const float* __restrict__ yv, const float* __restrict__ zv,
    const int* __restrict__ offsets, const int* __restrict__ lengths,
    float* __restrict__ attn) {
  __shared__ float ybuf[MAXL];
  __shared__ float zbuf[MAXL];
  __shared__ float redA[4], redB[4], redC[4];
  const int s = blockIdx.x;
  const int off = offsets[s];
  const int L = lengths[s];
  const int t = threadIdx.x;
  const int lane = t & 63, wid = t >> 6;

  float lmax = -1e30f;
  for (int i = t; i < L; i += 256) {
    float yy = yv[off + i];
    ybuf[i] = yy;
    zbuf[i] = zv[off + i];
    lmax = fmaxf(lmax, yy);
  }
  lmax = wave_reduce_max(lmax);
  if (lane == 0) redA[wid] = lmax;
  __syncthreads();
  const float ymax = fmaxf(fmaxf(redA[0], redA[1]), fmaxf(redA[2], redA[3]));
  const float invL = 1.f / (float)L;
  __syncthreads();

  float sw = 0.f, smx = 0.f, sz = 0.f;
  for (int i = t; i < L; i += 256) {
    float wgt = __expf(ybuf[i] - ymax);
    float xp = (float)(i + 1) * invL;
    sw += wgt;
    smx = fmaf(xp, wgt, smx);
    sz += zbuf[i];
  }
  sw = wave_reduce_sum(sw);
  smx = wave_reduce_sum(smx);
  sz = wave_reduce_sum(sz);
  if (lane == 0) { redA[wid] = sw; redB[wid] = smx; redC[wid] = sz; }
  __syncthreads();
  const float wsum = redA[0] + redA[1] + redA[2] + redA[3];
  const float mxs  = redB[0] + redB[1] + redB[2] + redB[3];
  const float zsum = redC[0] + redC[1] + redC[2] + redC[3];
  const float mu = mxs / wsum;
  const float tz = zsum * invL;
  const float sd = fmaxf(tz, 0.f) + log1pf(__expf(-fabsf(tz)));  // softplus
  const float invsd = 1.f / sd;
  const float C = 0.3989422804014327f;  // 1/sqrt(2*pi)
  __syncthreads();

  float ps = 0.f;
  for (int i = t; i < L; i += 256) {
    float xp = (float)(i + 1) * invL;
    float u = (xp - mu) * invsd;
    float p = __expf(-0.5f * u * u) * (C * invsd);
    ybuf[i] = p;
    ps += p;
  }
  ps = wave_reduce_sum(ps);
  if (lane == 0) redA[wid] = ps;
  __syncthreads();
  const float psum = redA[0] + redA[1] + redA[2] + redA[3];
  const float sc = 1.f / (psum + 0.001f);
  for (int i = t; i < L; i += 256) attn[off + i] = ybuf[i] * sc;
}

// ---------------------------------------------------------------------------
// K3: pooled output.  out[s,f] = sum_i attn_i * x[i,f].
// Grid (S, 32 chunks); thread = one feature; atomicAdd partials.
// ---------------------------------------------------------------------------
__global__ __launch_bounds__(256) void pool_kernel(
    const float* __restrict__ x, const float* __restrict__ attn,
    const int* __restrict__ offsets, const int* __restrict__ lengths,
    float* __restrict__ out, int nchunks) {
  const int s = blockIdx.x, c = blockIdx.y;
  const int off = offsets[s], L = lengths[s];
  const int i0 = (int)((long long)L * c / nchunks);
  const int i1 = (int)((long long)L * (c + 1) / nchunks);
  const int f = threadIdx.x;
  float acc[4] = {0.f, 0.f, 0.f, 0.f};
  int i = i0;
  for (; i + 3 < i1; i += 4) {
#pragma unroll
    for (int q = 0; q < 4; ++q)
      acc[q] = fmaf(attn[off + i + q], x[(size_t)(off + i + q) * F + f], acc[q]);
  }
  for (; i < i1; ++i)
    acc[0] = fmaf(attn[off + i], x[(size_t)(off + i) * F + f], acc[0]);
  float a = (acc[0] + acc[1]) + (acc[2] + acc[3]);
  atomicAdd(&out[s * F + f], a);
}

// ---------------------------------------------------------------------------
extern "C" void kernel_launch(void* const* d_in, const int* in_sizes, int n_in,
                              void* d_out, int out_size, void* d_ws, size_t ws_size,
                              hipStream_t stream) {
  const float* x      = (const float*)d_in[0];
  const int* lengths  = (const int*)d_in[1];
  const float* W1     = (const float*)d_in[2];
  const float* b1     = (const float*)d_in[3];
  const float* W2     = (const float*)d_in[4];
  const float* b2     = (const float*)d_in[5];
  const int S = in_sizes[1];
  const int N = in_sizes[0] / F;

  float* out  = (float*)d_out;             // S*F
  float* attn = out + (size_t)S * F;       // N

  int*   offsets = (int*)d_ws;                       // 512 ints (2 KB)
  float* yv = (float*)d_ws + 512;                    // N floats
  float* zv = yv + N;                                // N floats
  unsigned short* whT = (unsigned short*)(zv + N);   // 32768 shorts (64 KB)
  unsigned short* wlT = whT + F * Hh;                // 32768 shorts (64 KB)

  init_kernel<<<64, 256, 0, stream>>>(lengths, offsets, out, W1, whT, wlT, S, S * F);
  mlp_kernel<<<(N + 127) / 128, 256, 0, stream>>>(x, whT, wlT, b1, W2, b2, yv, zv, N);
  stats_kernel<<<S, 256, 0, stream>>>(yv, zv, offsets, lengths, attn);
  pool_kernel<<<dim3(S, 32), 256, 0, stream>>>(x, attn, offsets, lengths, out, 32);
}

// Round 3
// 462.487 us; speedup vs baseline: 1.4338x; 1.1086x over previous
//
#include <hip/hip_runtime.h>
#include <math.h>

#define F 256
#define Hh 128
#define MAXL 3072

typedef short bf16x8 __attribute__((ext_vector_type(8)));
typedef float f32x4 __attribute__((ext_vector_type(4)));

__device__ inline unsigned short f2bf_rne(float f) {
  unsigned u = __float_as_uint(f);
  unsigned r = u + 0x7fff + ((u >> 16) & 1);
  return (unsigned short)(r >> 16);
}
__device__ inline float bf2f(unsigned short h) {
  return __uint_as_float((unsigned)h << 16);
}

// ---------------------------------------------------------------------------
// K0: zero out, prefix-scan lengths, split W1 into bf16 hi/lo transposed
// chunk-major:  whT[chunk][col][k]  (chunk = k/32, k local 0..31), 8 chunks.
// ---------------------------------------------------------------------------
__global__ void init_kernel(const int* __restrict__ lengths, int* __restrict__ offsets,
                            float* __restrict__ out, const float* __restrict__ W1,
                            unsigned short* __restrict__ whT, unsigned short* __restrict__ wlT,
                            int S, int outN) {
  int t = blockIdx.x * blockDim.x + threadIdx.x;
  int stride = gridDim.x * blockDim.x;
  for (int i = t; i < outN; i += stride) out[i] = 0.f;
  for (int i = t; i < F * Hh; i += stride) {
    int k = i >> 7, col = i & 127;
    float v = W1[i];
    unsigned short h = f2bf_rne(v);
    unsigned short l = f2bf_rne(v - bf2f(h));
    int dst = (k >> 5) * (128 * 32) + col * 32 + (k & 31);
    whT[dst] = h;
    wlT[dst] = l;
  }
  if (blockIdx.x == 0) {
    __shared__ int buf[256];
    int tid = threadIdx.x;
    int v = (tid < S) ? lengths[tid] : 0;
    buf[tid] = v;
    __syncthreads();
    for (int o = 1; o < 256; o <<= 1) {
      int add = (tid >= o) ? buf[tid - o] : 0;
      __syncthreads();
      buf[tid] += add;
      __syncthreads();
    }
    if (tid < S) offsets[tid] = buf[tid] - v;   // exclusive
    if (tid == S - 1) offsets[S] = buf[tid];    // total N
  }
}

// ---------------------------------------------------------------------------
// K1: fused MLP via MFMA, NO LDS staging, NO K-loop barriers.
// A fragments load directly from global x (32B contiguous per lane, 16 full
// 128B segments per inst), convert fp32->bf16 hi/lo in-register.
// B fragments load directly from pre-transposed whT/wlT (perfect 1KB/wave
// coalescing, 64KB L2-resident working set).
// Block: 128 rows x 128 cols, 4 waves in 2x2; wave = 4x4 16x16x32 tiles,
// 3 split-precision passes (hh + hl + lh).
// Epilogue: tanh + W2 contraction, shfl_xor reduce, 2KB LDS cross-wave sum.
// ---------------------------------------------------------------------------
__global__ __launch_bounds__(256) void mlp_kernel(
    const float* __restrict__ x,
    const unsigned short* __restrict__ whT, const unsigned short* __restrict__ wlT,
    const float* __restrict__ b1, const float* __restrict__ W2,
    const float* __restrict__ b2, float* __restrict__ yv,
    float* __restrict__ zv, int N) {
  __shared__ float redy[128][2];
  __shared__ float redz[128][2];

  const int t = threadIdx.x;
  const int lane = t & 63;
  const int w = t >> 6;
  const int wr = w >> 1, wc = w & 1;           // wave grid 2x2
  const int ln15 = lane & 15, lq = lane >> 4;  // quad

  const int row0 = blockIdx.x * 128;

  f32x4 acc[4][4];  // [rt][ct]
#pragma unroll
  for (int i = 0; i < 4; ++i)
#pragma unroll
    for (int j = 0; j < 4; ++j) acc[i][j] = (f32x4){0.f, 0.f, 0.f, 0.f};

  // per-lane row/col bases
  int rowg[4];
  bool rv[4];
#pragma unroll
  for (int rt = 0; rt < 4; ++rt) {
    rowg[rt] = row0 + wr * 64 + rt * 16 + ln15;
    rv[rt] = rowg[rt] < N;
  }
  const int cbase = wc * 64 + ln15;            // + ct*16

  for (int kc = 0; kc < 8; ++kc) {
    // ---- issue all global loads for this chunk first ----
    float4 av0[4], av1[4];
#pragma unroll
    for (int rt = 0; rt < 4; ++rt) {
      av0[rt] = make_float4(0.f, 0.f, 0.f, 0.f);
      av1[rt] = make_float4(0.f, 0.f, 0.f, 0.f);
      if (rv[rt]) {
        const float* p = &x[(size_t)rowg[rt] * F + kc * 32 + lq * 8];
        av0[rt] = *(const float4*)p;
        av1[rt] = *(const float4*)(p + 4);
      }
    }
    bf16x8 bh[4], bl[4];
#pragma unroll
    for (int ct = 0; ct < 4; ++ct) {
      int o = kc * 4096 + (cbase + ct * 16) * 32 + lq * 8;
      bh[ct] = *(const bf16x8*)&whT[o];
      bl[ct] = *(const bf16x8*)&wlT[o];
    }
    // ---- convert + MFMA ----
#pragma unroll
    for (int rt = 0; rt < 4; ++rt) {
      float f[8] = {av0[rt].x, av0[rt].y, av0[rt].z, av0[rt].w,
                    av1[rt].x, av1[rt].y, av1[rt].z, av1[rt].w};
      bf16x8 ah, al;
#pragma unroll
      for (int q = 0; q < 8; ++q) {
        unsigned short h = f2bf_rne(f[q]);
        ah[q] = (short)h;
        al[q] = (short)f2bf_rne(f[q] - bf2f(h));
      }
#pragma unroll
      for (int ct = 0; ct < 4; ++ct) {
        acc[rt][ct] = __builtin_amdgcn_mfma_f32_16x16x32_bf16(ah, bh[ct], acc[rt][ct], 0, 0, 0);
        acc[rt][ct] = __builtin_amdgcn_mfma_f32_16x16x32_bf16(ah, bl[ct], acc[rt][ct], 0, 0, 0);
        acc[rt][ct] = __builtin_amdgcn_mfma_f32_16x16x32_bf16(al, bh[ct], acc[rt][ct], 0, 0, 0);
      }
    }
  }

  // ---- epilogue: h = tanh(acc + b1), contract with W2 ----
  // acc[rt][ct][rg]: row = wr*64+rt*16+lq*4+rg, col = wc*64+ct*16+ln15
  float yp[4][4], zp[4][4];
#pragma unroll
  for (int i = 0; i < 4; ++i)
#pragma unroll
    for (int j = 0; j < 4; ++j) { yp[i][j] = 0.f; zp[i][j] = 0.f; }
#pragma unroll
  for (int ct = 0; ct < 4; ++ct) {
    int c = cbase + ct * 16;
    float b1c = b1[c], wyc = W2[2 * c], wzc = W2[2 * c + 1];
#pragma unroll
    for (int rt = 0; rt < 4; ++rt)
#pragma unroll
      for (int rg = 0; rg < 4; ++rg) {
        float a = acc[rt][ct][rg] + b1c;
        float e = __expf(2.f * a);
        float h = 1.f - __fdividef(2.f, e + 1.f);   // tanh(a)
        yp[rt][rg] = fmaf(h, wyc, yp[rt][rg]);
        zp[rt][rg] = fmaf(h, wzc, zp[rt][rg]);
      }
  }
  // reduce over the 16 ln15 lanes (cols) via shfl_xor, combine wc via LDS
#pragma unroll
  for (int rt = 0; rt < 4; ++rt)
#pragma unroll
    for (int rg = 0; rg < 4; ++rg) {
      float vy = yp[rt][rg], vz = zp[rt][rg];
#pragma unroll
      for (int m = 8; m; m >>= 1) {
        vy += __shfl_xor(vy, m);
        vz += __shfl_xor(vz, m);
      }
      if (ln15 == 0) {
        int row = wr * 64 + rt * 16 + lq * 4 + rg;
        redy[row][wc] = vy;
        redz[row][wc] = vz;
      }
    }
  __syncthreads();
  if (t < 128) {
    int g = row0 + t;
    if (g < N) {
      yv[g] = redy[t][0] + redy[t][1] + b2[0];
      zv[g] = redz[t][0] + redz[t][1] + b2[1];
    }
  }
}

// ---------------------------------------------------------------------------
// K2: per-segment stats + attention weights.  One 1024-thread block/segment.
// ---------------------------------------------------------------------------
__device__ inline float wave_reduce_sum(float v) {
#pragma unroll
  for (int o = 32; o; o >>= 1) v += __shfl_down(v, o);
  return v;
}
__device__ inline float wave_reduce_max(float v) {
#pragma unroll
  for (int o = 32; o; o >>= 1) v = fmaxf(v, __shfl_down(v, o));
  return v;
}

__global__ __launch_bounds__(1024) void stats_kernel(
    const float* __restrict__ yv, const float* __restrict__ zv,
    const int* __restrict__ offsets, const int* __restrict__ lengths,
    float* __restrict__ attn) {
  __shared__ float ybuf[MAXL];
  __shared__ float zbuf[MAXL];
  __shared__ float redA[16], redB[16], redC[16];
  const int s = blockIdx.x;
  const int off = offsets[s];
  const int L = lengths[s];
  const int t = threadIdx.x;
  const int lane = t & 63, wid = t >> 6;   // 16 waves

  float lmax = -1e30f;
  for (int i = t; i < L; i += 1024) {
    float yy = yv[off + i];
    ybuf[i] = yy;
    zbuf[i] = zv[off + i];
    lmax = fmaxf(lmax, yy);
  }
  lmax = wave_reduce_max(lmax);
  if (lane == 0) redA[wid] = lmax;
  __syncthreads();
  float ymax = redA[0];
#pragma unroll
  for (int q = 1; q < 16; ++q) ymax = fmaxf(ymax, redA[q]);
  const float invL = 1.f / (float)L;
  __syncthreads();

  float sw = 0.f, smx = 0.f, sz = 0.f;
  for (int i = t; i < L; i += 1024) {
    float wgt = __expf(ybuf[i] - ymax);
    float xp = (float)(i + 1) * invL;
    sw += wgt;
    smx = fmaf(xp, wgt, smx);
    sz += zbuf[i];
  }
  sw = wave_reduce_sum(sw);
  smx = wave_reduce_sum(smx);
  sz = wave_reduce_sum(sz);
  if (lane == 0) { redA[wid] = sw; redB[wid] = smx; redC[wid] = sz; }
  __syncthreads();
  float wsum = 0.f, mxs = 0.f, zsum = 0.f;
#pragma unroll
  for (int q = 0; q < 16; ++q) { wsum += redA[q]; mxs += redB[q]; zsum += redC[q]; }
  const float mu = mxs / wsum;
  const float tz = zsum * invL;
  const float sd = fmaxf(tz, 0.f) + log1pf(__expf(-fabsf(tz)));  // softplus
  const float invsd = 1.f / sd;
  const float C = 0.3989422804014327f;  // 1/sqrt(2*pi)
  __syncthreads();

  float ps = 0.f;
  for (int i = t; i < L; i += 1024) {
    float xp = (float)(i + 1) * invL;
    float u = (xp - mu) * invsd;
    float p = __expf(-0.5f * u * u) * (C * invsd);
    ybuf[i] = p;
    ps += p;
  }
  ps = wave_reduce_sum(ps);
  if (lane == 0) redA[wid] = ps;
  __syncthreads();
  float psum = 0.f;
#pragma unroll
  for (int q = 0; q < 16; ++q) psum += redA[q];
  const float sc = 1.f / (psum + 0.001f);
  for (int i = t; i < L; i += 1024) attn[off + i] = ybuf[i] * sc;
}

// ---------------------------------------------------------------------------
// K3: pooled output.  out[s,f] = sum_i attn_i * x[i,f].
// Grid (S, 32 chunks); 4 waves/block; wave = one row per iter, lane = float4
// of features (1KB/wave fully coalesced).  2 chains for ILP.
// ---------------------------------------------------------------------------
__global__ __launch_bounds__(256) void pool_kernel(
    const float* __restrict__ x, const float* __restrict__ attn,
    const int* __restrict__ offsets, const int* __restrict__ lengths,
    float* __restrict__ out, int nchunks) {
  __shared__ float4 sbuf[4][64];
  const int s = blockIdx.x, c = blockIdx.y;
  const int off = offsets[s], L = lengths[s];
  const int i0 = (int)((long long)L * c / nchunks);
  const int i1 = (int)((long long)L * (c + 1) / nchunks);
  const int t = threadIdx.x;
  const int lane = t & 63, wid = t >> 6;

  float4 a0 = make_float4(0.f, 0.f, 0.f, 0.f);
  float4 a1 = make_float4(0.f, 0.f, 0.f, 0.f);
  int i = i0 + wid;
  for (; i + 4 < i1; i += 8) {
    float w0 = attn[off + i];
    float w1 = attn[off + i + 4];
    float4 v0 = *(const float4*)&x[(size_t)(off + i) * F + lane * 4];
    float4 v1 = *(const float4*)&x[(size_t)(off + i + 4) * F + lane * 4];
    a0.x = fmaf(w0, v0.x, a0.x); a0.y = fmaf(w0, v0.y, a0.y);
    a0.z = fmaf(w0, v0.z, a0.z); a0.w = fmaf(w0, v0.w, a0.w);
    a1.x = fmaf(w1, v1.x, a1.x); a1.y = fmaf(w1, v1.y, a1.y);
    a1.z = fmaf(w1, v1.z, a1.z); a1.w = fmaf(w1, v1.w, a1.w);
  }
  if (i < i1) {
    float w0 = attn[off + i];
    float4 v0 = *(const float4*)&x[(size_t)(off + i) * F + lane * 4];
    a0.x = fmaf(w0, v0.x, a0.x); a0.y = fmaf(w0, v0.y, a0.y);
    a0.z = fmaf(w0, v0.z, a0.z); a0.w = fmaf(w0, v0.w, a0.w);
  }
  a0.x += a1.x; a0.y += a1.y; a0.z += a1.z; a0.w += a1.w;
  sbuf[wid][lane] = a0;
  __syncthreads();
  if (wid == 0) {
    float4 r0 = sbuf[0][lane], r1 = sbuf[1][lane];
    float4 r2 = sbuf[2][lane], r3 = sbuf[3][lane];
    float rx = (r0.x + r1.x) + (r2.x + r3.x);
    float ry = (r0.y + r1.y) + (r2.y + r3.y);
    float rz = (r0.z + r1.z) + (r2.z + r3.z);
    float rw = (r0.w + r1.w) + (r2.w + r3.w);
    float* o = &out[s * F + lane * 4];
    atomicAdd(o + 0, rx);
    atomicAdd(o + 1, ry);
    atomicAdd(o + 2, rz);
    atomicAdd(o + 3, rw);
  }
}

// ---------------------------------------------------------------------------
extern "C" void kernel_launch(void* const* d_in, const int* in_sizes, int n_in,
                              void* d_out, int out_size, void* d_ws, size_t ws_size,
                              hipStream_t stream) {
  const float* x      = (const float*)d_in[0];
  const int* lengths  = (const int*)d_in[1];
  const float* W1     = (const float*)d_in[2];
  const float* b1     = (const float*)d_in[3];
  const float* W2     = (const float*)d_in[4];
  const float* b2     = (const float*)d_in[5];
  const int S = in_sizes[1];
  const int N = in_sizes[0] / F;

  float* out  = (float*)d_out;             // S*F
  float* attn = out + (size_t)S * F;       // N

  int*   offsets = (int*)d_ws;                       // 512 ints (2 KB)
  float* yv = (float*)d_ws + 512;                    // N floats
  float* zv = yv + N;                                // N floats
  unsigned short* whT = (unsigned short*)(zv + N);   // 32768 shorts (64 KB)
  unsigned short* wlT = whT + F * Hh;                // 32768 shorts (64 KB)

  init_kernel<<<64, 256, 0, stream>>>(lengths, offsets, out, W1, whT, wlT, S, S * F);
  mlp_kernel<<<(N + 127) / 128, 256, 0, stream>>>(x, whT, wlT, b1, W2, b2, yv, zv, N);
  stats_kernel<<<S, 1024, 0, stream>>>(yv, zv, offsets, lengths, attn);
  pool_kernel<<<dim3(S, 32), 256, 0, stream>>>(x, attn, offsets, lengths, out, 32);
}

// Round 4
// 458.416 us; speedup vs baseline: 1.4465x; 1.0089x over previous
//
#include <hip/hip_runtime.h>
#include <math.h>

#define F 256
#define Hh 128
#define MAXL 3072

typedef short bf16x8 __attribute__((ext_vector_type(8)));
typedef float f32x4 __attribute__((ext_vector_type(4)));
typedef unsigned int uint4v __attribute__((ext_vector_type(4)));

__device__ inline unsigned short f2bf_rne(float f) {
  unsigned u = __float_as_uint(f);
  unsigned r = u + 0x7fff + ((u >> 16) & 1);
  return (unsigned short)(r >> 16);
}
__device__ inline float bf2f(unsigned short h) {
  return __uint_as_float((unsigned)h << 16);
}

// ---------------------------------------------------------------------------
// K0: zero out, prefix-scan lengths, split W1 into bf16 hi/lo transposed
// chunk-major:  whT[chunk][col][k]  (chunk = k/32, k local 0..31), 8 chunks.
// W1 split stays RNE (one-time cost, max precision on the hi term).
// ---------------------------------------------------------------------------
__global__ void init_kernel(const int* __restrict__ lengths, int* __restrict__ offsets,
                            float* __restrict__ out, const float* __restrict__ W1,
                            unsigned short* __restrict__ whT, unsigned short* __restrict__ wlT,
                            int S, int outN) {
  int t = blockIdx.x * blockDim.x + threadIdx.x;
  int stride = gridDim.x * blockDim.x;
  for (int i = t; i < outN; i += stride) out[i] = 0.f;
  for (int i = t; i < F * Hh; i += stride) {
    int k = i >> 7, col = i & 127;
    float v = W1[i];
    unsigned short h = f2bf_rne(v);
    unsigned short l = f2bf_rne(v - bf2f(h));
    int dst = (k >> 5) * (128 * 32) + col * 32 + (k & 31);
    whT[dst] = h;
    wlT[dst] = l;
  }
  if (blockIdx.x == 0) {
    __shared__ int buf[256];
    int tid = threadIdx.x;
    int v = (tid < S) ? lengths[tid] : 0;
    buf[tid] = v;
    __syncthreads();
    for (int o = 1; o < 256; o <<= 1) {
      int add = (tid >= o) ? buf[tid - o] : 0;
      __syncthreads();
      buf[tid] += add;
      __syncthreads();
    }
    if (tid < S) offsets[tid] = buf[tid] - v;   // exclusive
    if (tid == S - 1) offsets[S] = buf[tid];    // total N
  }
}

// ---------------------------------------------------------------------------
// K1: fused MLP via MFMA, no LDS staging, no K-loop barriers.
// A fragments: direct global loads of x (32B/lane), TRUNCATION split to
// bf16 hi/lo: hi = f & 0xFFFF0000 (residual exact), lo = trunc16(f - hi),
// packed pairwise with v_perm_b32 — 6 VALU per 2 elements (was ~20).
// B fragments: pre-split whT/wlT, perfectly coalesced, L2-resident.
// 3 MFMA passes (hh + hl + lh); dropped ll term ~2^-16 relative.
// ---------------------------------------------------------------------------
__global__ __launch_bounds__(256) void mlp_kernel(
    const float* __restrict__ x,
    const unsigned short* __restrict__ whT, const unsigned short* __restrict__ wlT,
    const float* __restrict__ b1, const float* __restrict__ W2,
    const float* __restrict__ b2, float* __restrict__ yv,
    float* __restrict__ zv, int N) {
  __shared__ float redy[128][2];
  __shared__ float redz[128][2];

  const int t = threadIdx.x;
  const int lane = t & 63;
  const int w = t >> 6;
  const int wr = w >> 1, wc = w & 1;           // wave grid 2x2
  const int ln15 = lane & 15, lq = lane >> 4;  // quad

  const int row0 = blockIdx.x * 128;

  f32x4 acc[4][4];  // [rt][ct]
#pragma unroll
  for (int i = 0; i < 4; ++i)
#pragma unroll
    for (int j = 0; j < 4; ++j) acc[i][j] = (f32x4){0.f, 0.f, 0.f, 0.f};

  int rowg[4];
  bool rv[4];
#pragma unroll
  for (int rt = 0; rt < 4; ++rt) {
    rowg[rt] = row0 + wr * 64 + rt * 16 + ln15;
    rv[rt] = rowg[rt] < N;
  }
  const int cbase = wc * 64 + ln15;            // + ct*16

  for (int kc = 0; kc < 8; ++kc) {
    // ---- issue all global loads for this chunk first ----
    float4 av0[4], av1[4];
#pragma unroll
    for (int rt = 0; rt < 4; ++rt) {
      av0[rt] = make_float4(0.f, 0.f, 0.f, 0.f);
      av1[rt] = make_float4(0.f, 0.f, 0.f, 0.f);
      if (rv[rt]) {
        const float* p = &x[(size_t)rowg[rt] * F + kc * 32 + lq * 8];
        av0[rt] = *(const float4*)p;
        av1[rt] = *(const float4*)(p + 4);
      }
    }
    bf16x8 bh[4], bl[4];
#pragma unroll
    for (int ct = 0; ct < 4; ++ct) {
      int o = kc * 4096 + (cbase + ct * 16) * 32 + lq * 8;
      bh[ct] = *(const bf16x8*)&whT[o];
      bl[ct] = *(const bf16x8*)&wlT[o];
    }
    // ---- cheap truncation split + MFMA ----
#pragma unroll
    for (int rt = 0; rt < 4; ++rt) {
      float f[8] = {av0[rt].x, av0[rt].y, av0[rt].z, av0[rt].w,
                    av1[rt].x, av1[rt].y, av1[rt].z, av1[rt].w};
      union { uint4v u; bf16x8 b; } ah, al;
#pragma unroll
      for (int q = 0; q < 4; ++q) {
        unsigned ua = __float_as_uint(f[2 * q]);
        unsigned ub = __float_as_uint(f[2 * q + 1]);
        // hi = upper-16 truncation, packed pairwise
        ah.u[q] = __builtin_amdgcn_perm(ub, ua, 0x07060302u);
        // exact residual, then truncate-pack
        float ra = f[2 * q]     - __uint_as_float(ua & 0xFFFF0000u);
        float rb = f[2 * q + 1] - __uint_as_float(ub & 0xFFFF0000u);
        al.u[q] = __builtin_amdgcn_perm(__float_as_uint(rb), __float_as_uint(ra), 0x07060302u);
      }
#pragma unroll
      for (int ct = 0; ct < 4; ++ct) {
        acc[rt][ct] = __builtin_amdgcn_mfma_f32_16x16x32_bf16(ah.b, bh[ct], acc[rt][ct], 0, 0, 0);
        acc[rt][ct] = __builtin_amdgcn_mfma_f32_16x16x32_bf16(ah.b, bl[ct], acc[rt][ct], 0, 0, 0);
        acc[rt][ct] = __builtin_amdgcn_mfma_f32_16x16x32_bf16(al.b, bh[ct], acc[rt][ct], 0, 0, 0);
      }
    }
  }

  // ---- epilogue: h = tanh(acc + b1), contract with W2 ----
  // acc[rt][ct][rg]: row = wr*64+rt*16+lq*4+rg, col = wc*64+ct*16+ln15
  float yp[4][4], zp[4][4];
#pragma unroll
  for (int i = 0; i < 4; ++i)
#pragma unroll
    for (int j = 0; j < 4; ++j) { yp[i][j] = 0.f; zp[i][j] = 0.f; }
#pragma unroll
  for (int ct = 0; ct < 4; ++ct) {
    int c = cbase + ct * 16;
    float b1c = b1[c], wyc = W2[2 * c], wzc = W2[2 * c + 1];
#pragma unroll
    for (int rt = 0; rt < 4; ++rt)
#pragma unroll
      for (int rg = 0; rg < 4; ++rg) {
        float a = acc[rt][ct][rg] + b1c;
        float e = __expf(2.f * a);
        float h = 1.f - __fdividef(2.f, e + 1.f);   // tanh(a)
        yp[rt][rg] = fmaf(h, wyc, yp[rt][rg]);
        zp[rt][rg] = fmaf(h, wzc, zp[rt][rg]);
      }
  }
#pragma unroll
  for (int rt = 0; rt < 4; ++rt)
#pragma unroll
    for (int rg = 0; rg < 4; ++rg) {
      float vy = yp[rt][rg], vz = zp[rt][rg];
#pragma unroll
      for (int m = 8; m; m >>= 1) {
        vy += __shfl_xor(vy, m);
        vz += __shfl_xor(vz, m);
      }
      if (ln15 == 0) {
        int row = wr * 64 + rt * 16 + lq * 4 + rg;
        redy[row][wc] = vy;
        redz[row][wc] = vz;
      }
    }
  __syncthreads();
  if (t < 128) {
    int g = row0 + t;
    if (g < N) {
      yv[g] = redy[t][0] + redy[t][1] + b2[0];
      zv[g] = redz[t][0] + redz[t][1] + b2[1];
    }
  }
}

// ---------------------------------------------------------------------------
// K2: per-segment stats + attention weights.  One 1024-thread block/segment.
// ---------------------------------------------------------------------------
__device__ inline float wave_reduce_sum(float v) {
#pragma unroll
  for (int o = 32; o; o >>= 1) v += __shfl_down(v, o);
  return v;
}
__device__ inline float wave_reduce_max(float v) {
#pragma unroll
  for (int o = 32; o; o >>= 1) v = fmaxf(v, __shfl_down(v, o));
  return v;
}

__global__ __launch_bounds__(1024) void stats_kernel(
    const float* __restrict__ yv, const float* __restrict__ zv,
    const int* __restrict__ offsets, const int* __restrict__ lengths,
    float* __restrict__ attn) {
  __shared__ float ybuf[MAXL];
  __shared__ float zbuf[MAXL];
  __shared__ float redA[16], redB[16], redC[16];
  const int s = blockIdx.x;
  const int off = offsets[s];
  const int L = lengths[s];
  const int t = threadIdx.x;
  const int lane = t & 63, wid = t >> 6;   // 16 waves

  float lmax = -1e30f;
  for (int i = t; i < L; i += 1024) {
    float yy = yv[off + i];
    ybuf[i] = yy;
    zbuf[i] = zv[off + i];
    lmax = fmaxf(lmax, yy);
  }
  lmax = wave_reduce_max(lmax);
  if (lane == 0) redA[wid] = lmax;
  __syncthreads();
  float ymax = redA[0];
#pragma unroll
  for (int q = 1; q < 16; ++q) ymax = fmaxf(ymax, redA[q]);
  const float invL = 1.f / (float)L;
  __syncthreads();

  float sw = 0.f, smx = 0.f, sz = 0.f;
  for (int i = t; i < L; i += 1024) {
    float wgt = __expf(ybuf[i] - ymax);
    float xp = (float)(i + 1) * invL;
    sw += wgt;
    smx = fmaf(xp, wgt, smx);
    sz += zbuf[i];
  }
  sw = wave_reduce_sum(sw);
  smx = wave_reduce_sum(smx);
  sz = wave_reduce_sum(sz);
  if (lane == 0) { redA[wid] = sw; redB[wid] = smx; redC[wid] = sz; }
  __syncthreads();
  float wsum = 0.f, mxs = 0.f, zsum = 0.f;
#pragma unroll
  for (int q = 0; q < 16; ++q) { wsum += redA[q]; mxs += redB[q]; zsum += redC[q]; }
  const float mu = mxs / wsum;
  const float tz = zsum * invL;
  const float sd = fmaxf(tz, 0.f) + log1pf(__expf(-fabsf(tz)));  // softplus
  const float invsd = 1.f / sd;
  const float C = 0.3989422804014327f;  // 1/sqrt(2*pi)
  __syncthreads();

  float ps = 0.f;
  for (int i = t; i < L; i += 1024) {
    float xp = (float)(i + 1) * invL;
    float u = (xp - mu) * invsd;
    float p = __expf(-0.5f * u * u) * (C * invsd);
    ybuf[i] = p;
    ps += p;
  }
  ps = wave_reduce_sum(ps);
  if (lane == 0) redA[wid] = ps;
  __syncthreads();
  float psum = 0.f;
#pragma unroll
  for (int q = 0; q < 16; ++q) psum += redA[q];
  const float sc = 1.f / (psum + 0.001f);
  for (int i = t; i < L; i += 1024) attn[off + i] = ybuf[i] * sc;
}

// ---------------------------------------------------------------------------
// K3: pooled output.  out[s,f] = sum_i attn_i * x[i,f].
// Grid (S, 32 chunks); 4 waves/block; wave = one row per iter, lane = float4
// of features (1KB/wave fully coalesced).  2 chains for ILP.
// ---------------------------------------------------------------------------
__global__ __launch_bounds__(256) void pool_kernel(
    const float* __restrict__ x, const float* __restrict__ attn,
    const int* __restrict__ offsets, const int* __restrict__ lengths,
    float* __restrict__ out, int nchunks) {
  __shared__ float4 sbuf[4][64];
  const int s = blockIdx.x, c = blockIdx.y;
  const int off = offsets[s], L = lengths[s];
  const int i0 = (int)((long long)L * c / nchunks);
  const int i1 = (int)((long long)L * (c + 1) / nchunks);
  const int t = threadIdx.x;
  const int lane = t & 63, wid = t >> 6;

  float4 a0 = make_float4(0.f, 0.f, 0.f, 0.f);
  float4 a1 = make_float4(0.f, 0.f, 0.f, 0.f);
  int i = i0 + wid;
  for (; i + 4 < i1; i += 8) {
    float w0 = attn[off + i];
    float w1 = attn[off + i + 4];
    float4 v0 = *(const float4*)&x[(size_t)(off + i) * F + lane * 4];
    float4 v1 = *(const float4*)&x[(size_t)(off + i + 4) * F + lane * 4];
    a0.x = fmaf(w0, v0.x, a0.x); a0.y = fmaf(w0, v0.y, a0.y);
    a0.z = fmaf(w0, v0.z, a0.z); a0.w = fmaf(w0, v0.w, a0.w);
    a1.x = fmaf(w1, v1.x, a1.x); a1.y = fmaf(w1, v1.y, a1.y);
    a1.z = fmaf(w1, v1.z, a1.z); a1.w = fmaf(w1, v1.w, a1.w);
  }
  if (i < i1) {
    float w0 = attn[off + i];
    float4 v0 = *(const float4*)&x[(size_t)(off + i) * F + lane * 4];
    a0.x = fmaf(w0, v0.x, a0.x); a0.y = fmaf(w0, v0.y, a0.y);
    a0.z = fmaf(w0, v0.z, a0.z); a0.w = fmaf(w0, v0.w, a0.w);
  }
  a0.x += a1.x; a0.y += a1.y; a0.z += a1.z; a0.w += a1.w;
  sbuf[wid][lane] = a0;
  __syncthreads();
  if (wid == 0) {
    float4 r0 = sbuf[0][lane], r1 = sbuf[1][lane];
    float4 r2 = sbuf[2][lane], r3 = sbuf[3][lane];
    float rx = (r0.x + r1.x) + (r2.x + r3.x);
    float ry = (r0.y + r1.y) + (r2.y + r3.y);
    float rz = (r0.z + r1.z) + (r2.z + r3.z);
    float rw = (r0.w + r1.w) + (r2.w + r3.w);
    float* o = &out[s * F + lane * 4];
    atomicAdd(o + 0, rx);
    atomicAdd(o + 1, ry);
    atomicAdd(o + 2, rz);
    atomicAdd(o + 3, rw);
  }
}

// ---------------------------------------------------------------------------
extern "C" void kernel_launch(void* const* d_in, const int* in_sizes, int n_in,
                              void* d_out, int out_size, void* d_ws, size_t ws_size,
                              hipStream_t stream) {
  const float* x      = (const float*)d_in[0];
  const int* lengths  = (const int*)d_in[1];
  const float* W1     = (const float*)d_in[2];
  const float* b1     = (const float*)d_in[3];
  const float* W2     = (const float*)d_in[4];
  const float* b2     = (const float*)d_in[5];
  const int S = in_sizes[1];
  const int N = in_sizes[0] / F;

  float* out  = (float*)d_out;             // S*F
  float* attn = out + (size_t)S * F;       // N

  int*   offsets = (int*)d_ws;                       // 512 ints (2 KB)
  float* yv = (float*)d_ws + 512;                    // N floats
  float* zv = yv + N;                                // N floats
  unsigned short* whT = (unsigned short*)(zv + N);   // 32768 shorts (64 KB)
  unsigned short* wlT = whT + F * Hh;                // 32768 shorts (64 KB)

  init_kernel<<<64, 256, 0, stream>>>(lengths, offsets, out, W1, whT, wlT, S, S * F);
  mlp_kernel<<<(N + 127) / 128, 256, 0, stream>>>(x, whT, wlT, b1, W2, b2, yv, zv, N);
  stats_kernel<<<S, 1024, 0, stream>>>(yv, zv, offsets, lengths, attn);
  pool_kernel<<<dim3(S, 32), 256, 0, stream>>>(x, attn, offsets, lengths, out, 32);
}